// Round 1
// baseline (189.858 us; speedup 1.0000x reference)
//
#include <hip/hip_runtime.h>
#include <hip/hip_bf16.h>
#include <cstdint>

// Problem constants
#define B_DIM 2048
#define H_DIM 1024
#define K_DIM 2048   // 2*H  (input | hidden)
#define N_DIM 4096   // 4*H  (gates f,i,o,c)

typedef unsigned short u16;
typedef __attribute__((ext_vector_type(8))) short bf16x8;
typedef __attribute__((ext_vector_type(4))) float f32x4;

__device__ __forceinline__ u16 f2bf(float f) {
    unsigned int u = __float_as_uint(f);
    u += 0x7FFFu + ((u >> 16) & 1u);   // round-to-nearest-even
    return (u16)(u >> 16);
}

__device__ __forceinline__ float sigmoid_f(float x) {
    return 1.0f / (1.0f + __expf(-x));
}

// ---------------------------------------------------------------------------
// Kernel 1: A = [input | hidden] as bf16, row-major 2048 x 2048
// ---------------------------------------------------------------------------
__global__ __launch_bounds__(256) void pack_A(const float* __restrict__ input,
                                              const float* __restrict__ hidden,
                                              u16* __restrict__ A) {
    int idx = (blockIdx.x * 256 + threadIdx.x) * 4;   // over 2048*2048
    int m = idx >> 11;           // / K_DIM
    int k = idx & (K_DIM - 1);
    const float* src = (k < H_DIM) ? (input + (size_t)m * H_DIM + k)
                                   : (hidden + (size_t)m * H_DIM + (k - H_DIM));
    float4 v = *(const float4*)src;
    ushort4 o;
    o.x = f2bf(v.x); o.y = f2bf(v.y); o.z = f2bf(v.z); o.w = f2bf(v.w);
    *(ushort4*)(A + idx) = o;
}

// ---------------------------------------------------------------------------
// Kernel 2: Bt[n][k] (4096 x 2048, N-major bf16) = W[k][n] transposed.
// n = gate*1024 + h, gate order (f,i,o,c) matches reference concat.
// k < 1024 -> W_gate (input weights), k >= 1024 -> U_gate (recurrent).
// LDS-tiled 32x32 transpose, +1 pad for bank-conflict-free reads.
// ---------------------------------------------------------------------------
__global__ __launch_bounds__(256) void pack_B(
    const float* __restrict__ w_f, const float* __restrict__ w_i,
    const float* __restrict__ w_o, const float* __restrict__ w_c,
    const float* __restrict__ u_f, const float* __restrict__ u_i,
    const float* __restrict__ u_o, const float* __restrict__ u_c,
    u16* __restrict__ Bt) {
    __shared__ float tile[32][33];
    const int z = blockIdx.z;
    const float* M;
    switch (z) {
        case 0: M = w_f; break;
        case 1: M = w_i; break;
        case 2: M = w_o; break;
        case 3: M = w_c; break;
        case 4: M = u_f; break;
        case 5: M = u_i; break;
        case 6: M = u_o; break;
        default: M = u_c; break;
    }
    const int g = z & 3;
    const int half = z >> 2;
    const int h0 = blockIdx.x * 32;
    const int k0 = blockIdx.y * 32;
    const int tx = threadIdx.x;   // 0..31
    const int ty = threadIdx.y;   // 0..7
#pragma unroll
    for (int r = 0; r < 4; r++)
        tile[ty + r * 8][tx] = M[(size_t)(k0 + ty + r * 8) * H_DIM + h0 + tx];
    __syncthreads();
#pragma unroll
    for (int r = 0; r < 4; r++) {
        int n = g * H_DIM + h0 + ty + r * 8;
        Bt[(size_t)n * K_DIM + half * H_DIM + k0 + tx] = f2bf(tile[tx][ty + r * 8]);
    }
}

// ---------------------------------------------------------------------------
// Kernel 3: C (2048 x 4096 fp32) = A (2048 x 2048) @ Bt^T  (Bt is N-major)
// 128x128 tile, BK=32, 256 threads = 4 waves in 2x2, each wave 4x4 MFMA
// 16x16x32 bf16 accs. LDS leading-dim padded to 40 (20-bank stride -> 2-way
// conflicts only, free per m136).
// ---------------------------------------------------------------------------
#define BM 128
#define BN 128
#define BK 32
#define LDSW 40

__global__ __launch_bounds__(256, 2) void gemm_bt(const u16* __restrict__ A,
                                                  const u16* __restrict__ Bt,
                                                  float* __restrict__ C) {
    __shared__ u16 As[BM * LDSW];
    __shared__ u16 Bs[BN * LDSW];
    const int t = threadIdx.x;
    const int m0 = blockIdx.y * BM;
    const int n0 = blockIdx.x * BN;
    const int wave = t >> 6;
    const int lane = t & 63;
    const int wr = wave >> 1;   // wave row in 2x2
    const int wc = wave & 1;    // wave col
    const int lrow = lane & 15; // m (A) / n (B) within 16
    const int quad = lane >> 4; // 0..3 -> k-chunk of 8

    f32x4 acc[4][4] = {};

    // staging: 128x32 bf16 tile = 512 x 16B chunks; 256 threads x 2 chunks
    const int r0 = t >> 2;            // row 0..63
    const int c0 = (t & 3) * 8;       // k-offset 0,8,16,24
    const u16* Ag0 = A + (size_t)(m0 + r0) * K_DIM + c0;
    const u16* Ag1 = Ag0 + (size_t)64 * K_DIM;
    const u16* Bg0 = Bt + (size_t)(n0 + r0) * K_DIM + c0;
    const u16* Bg1 = Bg0 + (size_t)64 * K_DIM;
    u16* As0 = As + r0 * LDSW + c0;
    u16* As1 = As0 + 64 * LDSW;
    u16* Bs0 = Bs + r0 * LDSW + c0;
    u16* Bs1 = Bs0 + 64 * LDSW;

    const u16* afr = As + (wr * 64 + lrow) * LDSW + quad * 8;
    const u16* bfr = Bs + (wc * 64 + lrow) * LDSW + quad * 8;

    for (int k0 = 0; k0 < K_DIM; k0 += BK) {
        int4 a0 = *(const int4*)(Ag0 + k0);
        int4 a1 = *(const int4*)(Ag1 + k0);
        int4 b0 = *(const int4*)(Bg0 + k0);
        int4 b1 = *(const int4*)(Bg1 + k0);
        __syncthreads();   // previous iter's frag reads complete
        *(int4*)As0 = a0;
        *(int4*)As1 = a1;
        *(int4*)Bs0 = b0;
        *(int4*)Bs1 = b1;
        __syncthreads();
        bf16x8 af[4], bf[4];
#pragma unroll
        for (int i = 0; i < 4; i++) af[i] = *(const bf16x8*)(afr + i * 16 * LDSW);
#pragma unroll
        for (int j = 0; j < 4; j++) bf[j] = *(const bf16x8*)(bfr + j * 16 * LDSW);
#pragma unroll
        for (int i = 0; i < 4; i++)
#pragma unroll
            for (int j = 0; j < 4; j++)
                acc[i][j] = __builtin_amdgcn_mfma_f32_16x16x32_bf16(
                    af[i], bf[j], acc[i][j], 0, 0, 0);
    }

    // C/D layout: col = lane&15, row = quad*4 + reg  [m89/m91-verified]
    const int crow = m0 + wr * 64 + quad * 4;
    const int ccol = n0 + wc * 64 + lrow;
#pragma unroll
    for (int i = 0; i < 4; i++)
#pragma unroll
        for (int j = 0; j < 4; j++) {
#pragma unroll
            for (int r = 0; r < 4; r++)
                C[(size_t)(crow + i * 16 + r) * N_DIM + ccol + j * 16] = acc[i][j][r];
        }
}

// ---------------------------------------------------------------------------
// Kernel 4: elementwise LSTM epilogue.
// f = sig(g0+b1), i = sig(g1+b2), o = sig(g2+b3), g = tanh(g3+b4)
// c = pre_cell*f + i*g ;  h = o*tanh(c)*mask
// out[0 .. B*H)   = h
// out[B*H .. 2BH) = c
// ---------------------------------------------------------------------------
__global__ __launch_bounds__(256) void lstm_epilogue(
    const float* __restrict__ gates, const float* __restrict__ pre_cell,
    const float* __restrict__ b1, const float* __restrict__ b2,
    const float* __restrict__ b3, const float* __restrict__ b4,
    const float* __restrict__ mask, float* __restrict__ out) {
    int idx = (blockIdx.x * 256 + threadIdx.x) * 4;   // over B*H
    int m = idx >> 10;           // / H_DIM
    int h = idx & (H_DIM - 1);
    const float* grow = gates + (size_t)m * N_DIM + h;
    float4 gf = *(const float4*)(grow);
    float4 gi = *(const float4*)(grow + H_DIM);
    float4 go = *(const float4*)(grow + 2 * H_DIM);
    float4 gg = *(const float4*)(grow + 3 * H_DIM);
    float4 vb1 = *(const float4*)(b1 + h);
    float4 vb2 = *(const float4*)(b2 + h);
    float4 vb3 = *(const float4*)(b3 + h);
    float4 vb4 = *(const float4*)(b4 + h);
    float4 pc = *(const float4*)(pre_cell + idx);
    float4 mk = *(const float4*)(mask + idx);

    float4 oh, oc;
    const float* pgf = (const float*)&gf;
    const float* pgi = (const float*)&gi;
    const float* pgo = (const float*)&go;
    const float* pgg = (const float*)&gg;
    const float* pb1 = (const float*)&vb1;
    const float* pb2 = (const float*)&vb2;
    const float* pb3 = (const float*)&vb3;
    const float* pb4 = (const float*)&vb4;
    const float* ppc = (const float*)&pc;
    const float* pmk = (const float*)&mk;
    float* poh = (float*)&oh;
    float* poc = (float*)&oc;
#pragma unroll
    for (int q = 0; q < 4; q++) {
        float fv = sigmoid_f(pgf[q] + pb1[q]);
        float iv = sigmoid_f(pgi[q] + pb2[q]);
        float ov = sigmoid_f(pgo[q] + pb3[q]);
        float gv = tanhf(pgg[q] + pb4[q]);
        float cv = ppc[q] * fv + iv * gv;
        poc[q] = cv;
        poh[q] = ov * tanhf(cv) * pmk[q];
    }
    *(float4*)(out + idx) = oh;
    *(float4*)(out + (size_t)B_DIM * H_DIM + idx) = oc;
}

// ---------------------------------------------------------------------------
extern "C" void kernel_launch(void* const* d_in, const int* in_sizes, int n_in,
                              void* d_out, int out_size, void* d_ws, size_t ws_size,
                              hipStream_t stream) {
    const float* input    = (const float*)d_in[0];
    const float* hidden   = (const float*)d_in[1];
    const float* pre_cell = (const float*)d_in[2];
    const float* w_i = (const float*)d_in[3];
    const float* w_f = (const float*)d_in[4];
    const float* w_o = (const float*)d_in[5];
    const float* w_c = (const float*)d_in[6];
    const float* u_i = (const float*)d_in[7];
    const float* u_f = (const float*)d_in[8];
    const float* u_o = (const float*)d_in[9];
    const float* u_c = (const float*)d_in[10];
    const float* b1  = (const float*)d_in[11];
    const float* b2  = (const float*)d_in[12];
    const float* b3  = (const float*)d_in[13];
    const float* b4  = (const float*)d_in[14];
    const float* mask = (const float*)d_in[15];
    float* out = (float*)d_out;

    // workspace layout: A bf16 (8 MiB) | Bt bf16 (16 MiB) | gates fp32 (32 MiB)
    char* ws = (char*)d_ws;
    u16*  A     = (u16*)ws;                                  // 2048*2048*2
    u16*  Bt    = (u16*)(ws + (size_t)8 * 1024 * 1024);      // 4096*2048*2
    float* gates = (float*)(ws + (size_t)24 * 1024 * 1024);  // 2048*4096*4

    pack_A<<<dim3((B_DIM * K_DIM) / (256 * 4)), dim3(256), 0, stream>>>(input, hidden, A);
    pack_B<<<dim3(32, 32, 8), dim3(32, 8), 0, stream>>>(w_f, w_i, w_o, w_c,
                                                        u_f, u_i, u_o, u_c, Bt);
    gemm_bt<<<dim3(N_DIM / BN, B_DIM / BM), dim3(256), 0, stream>>>(A, Bt, gates);
    lstm_epilogue<<<dim3((B_DIM * H_DIM) / (256 * 4)), dim3(256), 0, stream>>>(
        gates, pre_cell, b1, b2, b3, b4, mask, out);
}

// Round 2
// 179.514 us; speedup vs baseline: 1.0576x; 1.0576x over previous
//
#include <hip/hip_runtime.h>
#include <hip/hip_bf16.h>
#include <cstdint>

// Problem constants
#define B_DIM 2048
#define H_DIM 1024
#define K_DIM 2048   // 2*H  (input | hidden)
#define N_DIM 4096   // 4*H  (gates, interleaved n' = 4*h + gate)

typedef unsigned short u16;
typedef __attribute__((ext_vector_type(8))) short bf16x8;
typedef __attribute__((ext_vector_type(8))) unsigned short u16x8;
typedef __attribute__((ext_vector_type(4))) float f32x4;

__device__ __forceinline__ u16 f2bf(float f) {
    unsigned int u = __float_as_uint(f);
    u += 0x7FFFu + ((u >> 16) & 1u);   // round-to-nearest-even
    return (u16)(u >> 16);
}

__device__ __forceinline__ float sigmoid_f(float x) {
    return 1.0f / (1.0f + __expf(-x));
}

// tanh via exp, saturating form (no inf/inf NaN at large |x|)
__device__ __forceinline__ float tanh_f(float x) {
    float e = __expf(2.0f * x);
    return 1.0f - 2.0f / (e + 1.0f);
}

// async global->LDS 16B per lane. LDS dest is wave-uniform base + lane*16:
// caller must ensure lane l's lptr == firstlane(lptr) + 16*l.
__device__ __forceinline__ void async16(const u16* g, u16* l) {
    __builtin_amdgcn_global_load_lds(
        (const __attribute__((address_space(1))) unsigned int*)g,
        (__attribute__((address_space(3))) unsigned int*)l,
        16, 0, 0);
}

// ---------------------------------------------------------------------------
// Kernel 1: A = [input | hidden] as bf16, row-major 2048 x 2048
// ---------------------------------------------------------------------------
__global__ __launch_bounds__(256) void pack_A(const float* __restrict__ input,
                                              const float* __restrict__ hidden,
                                              u16* __restrict__ A) {
    int idx = (blockIdx.x * 256 + threadIdx.x) * 4;   // over 2048*2048
    int m = idx >> 11;           // / K_DIM
    int k = idx & (K_DIM - 1);
    const float* src = (k < H_DIM) ? (input + (size_t)m * H_DIM + k)
                                   : (hidden + (size_t)m * H_DIM + (k - H_DIM));
    float4 v = *(const float4*)src;
    ushort4 o;
    o.x = f2bf(v.x); o.y = f2bf(v.y); o.z = f2bf(v.z); o.w = f2bf(v.w);
    *(ushort4*)(A + idx) = o;
}

// ---------------------------------------------------------------------------
// Kernel 2: Bt[n'][k] (4096 x 2048, bf16), n' = 4*h + gate (f,i,o,c).
// k < 1024 -> W_gate[k][h], k >= 1024 -> U_gate[k-1024][h].
// 32h x 64k tile via LDS; 16B vectorized stores (was 2B scalar -> slow).
// ---------------------------------------------------------------------------
__global__ __launch_bounds__(256) void pack_B(
    const float* __restrict__ w_f, const float* __restrict__ w_i,
    const float* __restrict__ w_o, const float* __restrict__ w_c,
    const float* __restrict__ u_f, const float* __restrict__ u_i,
    const float* __restrict__ u_o, const float* __restrict__ u_c,
    u16* __restrict__ Bt) {
    __shared__ float tile[32][65];   // [h][k], pad 65 vs 64
    const int z = blockIdx.z;
    const float* M;
    switch (z) {
        case 0: M = w_f; break;
        case 1: M = w_i; break;
        case 2: M = w_o; break;
        case 3: M = w_c; break;
        case 4: M = u_f; break;
        case 5: M = u_i; break;
        case 6: M = u_o; break;
        default: M = u_c; break;
    }
    const int g = z & 3;
    const int half = z >> 2;
    const int h0 = blockIdx.x * 32;
    const int k0 = blockIdx.y * 64;
    const int t = threadIdx.x;
#pragma unroll
    for (int it = 0; it < 2; it++) {
        int kl = (t >> 3) + it * 32;          // 0..63
        int hl = (t & 7) * 4;                 // 0..28
        float4 v = *(const float4*)(M + (size_t)(k0 + kl) * H_DIM + h0 + hl);
        tile[hl + 0][kl] = v.x;
        tile[hl + 1][kl] = v.y;
        tile[hl + 2][kl] = v.z;
        tile[hl + 3][kl] = v.w;
    }
    __syncthreads();
    {
        int hl = t >> 3;                      // 0..31
        int ko = (t & 7) * 8;                 // 0..56
        u16x8 o;
#pragma unroll
        for (int q = 0; q < 8; q++) o[q] = f2bf(tile[hl][ko + q]);
        size_t n = 4 * (size_t)(h0 + hl) + g;
        *(u16x8*)(Bt + n * K_DIM + half * H_DIM + k0 + ko) = o;
    }
}

// ---------------------------------------------------------------------------
// Kernel 3: bias_il[4h+g] = b_{g}[h]   (f,i,o,c -> bias1..bias4)
// ---------------------------------------------------------------------------
__global__ __launch_bounds__(256) void pack_bias(
    const float* __restrict__ b1, const float* __restrict__ b2,
    const float* __restrict__ b3, const float* __restrict__ b4,
    float* __restrict__ bias_il) {
    int idx = blockIdx.x * 256 + threadIdx.x;   // < 4096
    int h = idx >> 2, g = idx & 3;
    const float* b = (g == 0) ? b1 : (g == 1) ? b2 : (g == 2) ? b3 : b4;
    bias_il[idx] = b[h];
}

// ---------------------------------------------------------------------------
// Kernel 4: fused GEMM + LSTM epilogue.
// C[m][n'] = bias_il[n'] + A[m][:] . Bt[n'][:]   (n' = 4h+g, all 4 gates of an
// h are inside one 128-col tile). After the K loop, each j-chunk (16 cols x 2
// wave-cols = 32 cols) is round-tripped through LDS to regroup gate quads,
// then sigmoid/tanh/c/h computed and stored directly -> no gates buffer.
// m97-style staging: global_load_lds width-16, unpadded 64B LDS rows.
// ---------------------------------------------------------------------------
#define BM 128
#define BN 128
#define BK 32

__global__ __launch_bounds__(256, 2) void gemm_fused(
    const u16* __restrict__ A, const u16* __restrict__ Bt,
    const float* __restrict__ bias_il, const float* __restrict__ pre_cell,
    const float* __restrict__ mask, float* __restrict__ out) {
    __shared__ char smem[17408];
    u16* As = (u16*)smem;                 // 128 x 32 bf16 = 8KB
    u16* Bs = (u16*)(smem + 8192);        // 128 x 32 bf16 = 8KB
    float* et = (float*)smem;             // epilogue reuse: [128][33] f32

    const int t = threadIdx.x;
    const int w = t >> 6, l = t & 63;
    const int m0 = blockIdx.y * BM;
    const int n0 = blockIdx.x * BN;
    const int wr = w >> 1;    // wave row in 2x2
    const int wc = w & 1;     // wave col
    const int lrow = l & 15;  // m (A) / n (B) within 16
    const int quad = l >> 4;  // 0..3 -> k-chunk of 8

    // staging: lane l of wave w covers row w*16+(l>>2) (+64 for 2nd issue),
    // k-offset (l&3)*8. LDS addr = base + 16*l  (global_load_lds constraint).
    const int sr = w * 16 + (l >> 2);
    const int sc = (l & 3) * 8;
    const u16* Ag0 = A + (size_t)(m0 + sr) * K_DIM + sc;
    const u16* Ag1 = Ag0 + (size_t)64 * K_DIM;
    const u16* Bg0 = Bt + (size_t)(n0 + sr) * K_DIM + sc;
    const u16* Bg1 = Bg0 + (size_t)64 * K_DIM;
    u16* Al0 = As + sr * BK + sc;
    u16* Al1 = Al0 + 64 * BK;
    u16* Bl0 = Bs + sr * BK + sc;
    u16* Bl1 = Bl0 + 64 * BK;

    const u16* afr = As + (wr * 64 + lrow) * BK + quad * 8;
    const u16* bfr = Bs + (wc * 64 + lrow) * BK + quad * 8;

    // acc init = bias (bias is constant down a column; lane col = per-j fixed)
    f32x4 acc[4][4];
#pragma unroll
    for (int j = 0; j < 4; j++) {
        float bv = bias_il[n0 + wc * 64 + j * 16 + lrow];
#pragma unroll
        for (int i = 0; i < 4; i++) acc[i][j] = (f32x4){bv, bv, bv, bv};
    }

    for (int k0 = 0; k0 < K_DIM; k0 += BK) {
        __syncthreads();          // previous iter's frag reads complete
        async16(Ag0 + k0, Al0);
        async16(Ag1 + k0, Al1);
        async16(Bg0 + k0, Bl0);
        async16(Bg1 + k0, Bl1);
        __syncthreads();          // drains vmcnt -> LDS visible
        bf16x8 af[4], bf[4];
#pragma unroll
        for (int i = 0; i < 4; i++) af[i] = *(const bf16x8*)(afr + i * 16 * BK);
#pragma unroll
        for (int j = 0; j < 4; j++) bf[j] = *(const bf16x8*)(bfr + j * 16 * BK);
#pragma unroll
        for (int i = 0; i < 4; i++)
#pragma unroll
            for (int j = 0; j < 4; j++)
                acc[i][j] = __builtin_amdgcn_mfma_f32_16x16x32_bf16(
                    af[i], bf[j], acc[i][j], 0, 0, 0);
    }

    // ---- fused LSTM epilogue ----
    // C/D layout: col = lane&15, row = quad*4 + reg  [m89/m91-verified]
    const int row = t >> 1;     // 0..127
    const int half = t & 1;     // 0 -> wc=0 cols, 1 -> wc=1 cols
    const size_t orow = (size_t)(m0 + row) * H_DIM;
#pragma unroll
    for (int j = 0; j < 4; j++) {
        __syncthreads();        // et aliases As/Bs; prior reads complete
#pragma unroll
        for (int i = 0; i < 4; i++)
#pragma unroll
            for (int r = 0; r < 4; r++)
                et[(wr * 64 + i * 16 + quad * 4 + r) * 33 + wc * 16 + lrow] =
                    acc[i][j][r];
        __syncthreads();
        // thread t handles row, 4 h-values of one wave-col half
        const int hg0 = (n0 >> 2) + half * 16 + j * 4;
        const float* ep = et + row * 33 + half * 16;  // 4h x 4gates = 16 f32
        float4 pc = *(const float4*)(pre_cell + orow + hg0);
        float4 mk = *(const float4*)(mask + orow + hg0);
        const float* ppc = (const float*)&pc;
        const float* pmk = (const float*)&mk;
        float4 oh, oc;
        float* poh = (float*)&oh;
        float* poc = (float*)&oc;
#pragma unroll
        for (int q = 0; q < 4; q++) {
            float fv = sigmoid_f(ep[4 * q + 0]);
            float iv = sigmoid_f(ep[4 * q + 1]);
            float ov = sigmoid_f(ep[4 * q + 2]);
            float gv = tanh_f(ep[4 * q + 3]);
            float cv = ppc[q] * fv + iv * gv;
            poc[q] = cv;
            poh[q] = ov * tanh_f(cv) * pmk[q];
        }
        *(float4*)(out + orow + hg0) = oh;
        *(float4*)(out + (size_t)B_DIM * H_DIM + orow + hg0) = oc;
    }
}

// ---------------------------------------------------------------------------
extern "C" void kernel_launch(void* const* d_in, const int* in_sizes, int n_in,
                              void* d_out, int out_size, void* d_ws, size_t ws_size,
                              hipStream_t stream) {
    const float* input    = (const float*)d_in[0];
    const float* hidden   = (const float*)d_in[1];
    const float* pre_cell = (const float*)d_in[2];
    const float* w_i = (const float*)d_in[3];
    const float* w_f = (const float*)d_in[4];
    const float* w_o = (const float*)d_in[5];
    const float* w_c = (const float*)d_in[6];
    const float* u_i = (const float*)d_in[7];
    const float* u_f = (const float*)d_in[8];
    const float* u_o = (const float*)d_in[9];
    const float* u_c = (const float*)d_in[10];
    const float* b1  = (const float*)d_in[11];
    const float* b2  = (const float*)d_in[12];
    const float* b3  = (const float*)d_in[13];
    const float* b4  = (const float*)d_in[14];
    const float* mask = (const float*)d_in[15];
    float* out = (float*)d_out;

    // workspace: A bf16 (8 MiB) | Bt bf16 (16 MiB) | bias_il (16 KiB)
    char* ws = (char*)d_ws;
    u16*   A       = (u16*)ws;
    u16*   Bt      = (u16*)(ws + (size_t)8 * 1024 * 1024);
    float* bias_il = (float*)(ws + (size_t)24 * 1024 * 1024);

    pack_A<<<dim3((B_DIM * K_DIM) / (256 * 4)), dim3(256), 0, stream>>>(input, hidden, A);
    pack_B<<<dim3(32, 16, 8), dim3(256), 0, stream>>>(w_f, w_i, w_o, w_c,
                                                      u_f, u_i, u_o, u_c, Bt);
    pack_bias<<<dim3(16), dim3(256), 0, stream>>>(b1, b2, b3, b4, bias_il);
    gemm_fused<<<dim3(N_DIM / BN, B_DIM / BM), dim3(256), 0, stream>>>(
        A, Bt, bias_il, pre_cell, mask, out);
}